// Round 6
// baseline (222.656 us; speedup 1.0000x reference)
//
#include <hip/hip_runtime.h>

#define N_TOK 4096
#define DIM   1024

typedef __bf16 bf16x8 __attribute__((ext_vector_type(8)));
typedef float  f32x4  __attribute__((ext_vector_type(4)));

__device__ __forceinline__ unsigned short f2bf(float f) {
  union { float f; unsigned u; } v; v.f = f;
  unsigned u = v.u;
  return (unsigned short)((u + 0x7fffu + ((u >> 16) & 1u)) >> 16);
}
__device__ __forceinline__ float bf2f(unsigned short h) {
  union { unsigned u; float f; } v; v.u = ((unsigned)h) << 16;
  return v.f;
}

// async global->LDS, 16 B/lane: lane's data lands at (uniform lds base) + lane*16
__device__ __forceinline__ void gll16(const unsigned short* g,
                                      unsigned short* l) {
  __builtin_amdgcn_global_load_lds(
      (const __attribute__((address_space(1))) unsigned int*)g,
      (__attribute__((address_space(3))) unsigned int*)l, 16, 0, 0);
}

// ---------------------------------------------------------------------------
// prep kernel.  ZERO job covers out rows 512..4095 (EPI3 chunk-512 makes
// rows >= 512 atomic-accumulated): 896 blk * 256 thr * 4 float4 =
// 917504 float4 = 3584 rows EXACT.
// ---------------------------------------------------------------------------
#define PB_CVT 0
#define PB_TQ 2048
#define PB_ZERO 5120
#define PB_LSUM 6016
#define PB_BIAS 6020
#define PB_TOTAL 6023

__global__ void prep(const float* __restrict__ x, const float* __restrict__ Wq,
                     const float* __restrict__ Wk, const float* __restrict__ Wv,
                     const float* __restrict__ bq, const float* __restrict__ bk,
                     const float* __restrict__ bv,
                     unsigned short* __restrict__ xb,
                     unsigned short* __restrict__ Wt,
                     float* __restrict__ out, float* __restrict__ ball,
                     float* __restrict__ Lsum) {
  const int b = blockIdx.x;
  const int t = threadIdx.x;
  if (b < PB_TQ) {  // CVT
    const int i = ((b - PB_CVT) * 256 + t) * 8;
    float4 v0 = *(const float4*)(x + i);
    float4 v1 = *(const float4*)(x + i + 4);
    ushort4 r0, r1;
    r0.x = f2bf(v0.x); r0.y = f2bf(v0.y); r0.z = f2bf(v0.z); r0.w = f2bf(v0.w);
    r1.x = f2bf(v1.x); r1.y = f2bf(v1.y); r1.z = f2bf(v1.z); r1.w = f2bf(v1.w);
    *(ushort4*)(xb + i) = r0;
    *(ushort4*)(xb + i + 4) = r1;
  } else if (b < PB_ZERO) {  // transpose one 32x32 tile of one W
    const int which = (b - PB_TQ) >> 10;          // 0,1,2
    const int lb = (b - PB_TQ) & 1023;
    const float* W = (which == 0) ? Wq : (which == 1) ? Wk : Wv;
    unsigned short* D = Wt + (size_t)which * 1024 * 1024;
    __shared__ float tile[32][33];
    const int bx = (lb & 31) * 32, by = (lb >> 5) * 32;
    const int tx = t & 31, ty = t >> 5;  // ty in 0..7
    for (int r = ty; r < 32; r += 8)
      tile[r][tx] = W[(size_t)(by + r) * DIM + bx + tx];
    __syncthreads();
    for (int r = ty; r < 32; r += 8)
      D[(size_t)(bx + r) * DIM + by + tx] = f2bf(tile[tx][r]);
  } else if (b < PB_LSUM) {  // zero out rows >= 512 (3584 rows, exact)
    float4* p = (float4*)(out + (size_t)512 * DIM);
    const int i = ((b - PB_ZERO) * 256 + t) * 4;
#pragma unroll
    for (int c = 0; c < 4; c++) p[i + c] = make_float4(0.f, 0.f, 0.f, 0.f);
  } else if (b < PB_BIAS) {  // Lsum zero
    const int i = ((b - PB_LSUM) * 256 + t) * 4;
    *(float4*)(Lsum + i) = make_float4(0.f, 0.f, 0.f, 0.f);
  } else {  // bias, 4/thread
    const int i = ((b - PB_BIAS) * 256 + t) * 4;
#pragma unroll
    for (int c = 0; c < 4; c++) {
      const int k = i + c;
      if (k < 3072)
        ball[k] = (k < 1024) ? bq[k] * 0.03125f
                             : ((k < 2048) ? bk[k - 1024] : bv[k - 2048]);
    }
  }
}

// ---------------------------------------------------------------------------
// A·B^T MFMA GEMM — round-5 proven structure (128x128 tile, 4 waves, BK=64,
// single-buffer 32 KB LDS drain loop, VGPR~64, stream-count = blocks/CU is
// the perf knob per r5 data) + this round's deltas:
//  * EPI3: split-K chunk 512 (z<=8) -> 1152 blocks = 4.5 streams/CU (was
//    2.5). Decode i -> (bn=i&7, q=i>>3); q -> band b (bm in [4b,4b+3],
//    b+1 chunks each, band start 2b(b+1)). bn=i&7 keeps each XCD pinned to
//    one 1MB V^T panel (L2-resident) under round-robin dispatch.
//  * EPI0/EPI2: XCD-chunked bijective swizzle (nwg%8==0 exact) — clusters
//    same-A-tile blocks on one XCD's L2 instead of 8-way thrash.
//  * T2 swizzle (0 conflicts, verified): linear gll16 dest, source chunk
//    pre-XOR'd by row&7, read offset ^ ((lane&7)<<3).
//  * EPI0 fuses V^T emission (transpose kernel deleted).
// ---------------------------------------------------------------------------
#define BK 64

template <int EPI>
__global__ void gemm_tn(const unsigned short* __restrict__ A,
                        const unsigned short* __restrict__ B,
                        void* __restrict__ Cout,
                        const float* __restrict__ bias,
                        float* __restrict__ Lsum,
                        unsigned short* __restrict__ VT,
                        int K, int lda, int ldb, int ldc) {
  int bm, bn, kbeg, kend;
  bool single = true;
  if (EPI == 3) {
    const int i = blockIdx.x;        // 0..1151
    bn = i & 7;                      // XCD-aligned V^T panel
    const int q = i >> 3;            // 0..143
    int b = (int)((sqrtf(2.f * (float)q + 1.f) - 1.f) * 0.5f);
    while (2 * (b + 1) * (b + 2) <= q) ++b;
    while (2 * b * (b + 1) > q) --b;
    const int r = q - 2 * b * (b + 1);
    bm = 4 * b + (r & 3);
    const int z = r >> 2;            // 0..b
    const int Keff = (bm + 1) * 128;
    kbeg = z * 512;
    kend = min(kbeg + 512, Keff);
    single = (Keff <= 512);
  } else if (EPI == 2) {
    // XCD-chunked swizzle (528 = 8*66), then triangular decode
    const int id = blockIdx.x;
    const int wg = (id & 7) * 66 + (id >> 3);
    float s = sqrtf(8.f * (float)wg + 1.f);
    bm = (int)((s - 1.f) * 0.5f);
    while ((bm + 1) * (bm + 2) / 2 <= wg) ++bm;
    while (bm * (bm + 1) / 2 > wg) --bm;
    bn = wg - bm * (bm + 1) / 2;     // 0..bm
    kbeg = 0; kend = K;
  } else {
    // XCD-chunked swizzle (768 = 8*96)
    const int id = blockIdx.y * gridDim.x + blockIdx.x;
    const int wg = (id & 7) * 96 + (id >> 3);
    bm = wg / 24; bn = wg % 24;
    kbeg = 0; kend = K;
  }

  __shared__ __align__(16) unsigned short smA[128 * 64];
  __shared__ __align__(16) unsigned short smB[128 * 64];

  const int t = threadIdx.x;
  const int lane = t & 63, w = t >> 6;
  const int wm = (w & 1) * 64, wn = (w >> 1) * 64;

  f32x4 acc[4][4] = {};

  const unsigned short* Ab = A + (size_t)bm * 128 * lda;
  const unsigned short* Bb = B + (size_t)bn * 128 * ldb;

  const int rA = wm + (lane & 15);
  const int rB = wn + (lane & 15);
  const int kquad = (lane >> 4) << 3;
  const int swz = (lane & 7) << 3;   // read-side XOR (shorts)

  // staging source: row lr = lane>>3, chunk pre-XOR'd by lr so the linear
  // gll16 write matches the swizzled read (read rows have row&7 == lane&7).
  const int lr = lane >> 3;
  const int g8 = ((lane & 7) ^ lr) << 3;
  const unsigned short* pa = Ab + (size_t)lr * lda + g8 + kbeg;
  const unsigned short* pb = Bb + (size_t)lr * ldb + g8 + kbeg;

  for (int k0 = kbeg; k0 < kend; k0 += BK) {
    __syncthreads();
#pragma unroll
    for (int m = 0; m < 4; m++) {
      const int r0 = (w << 5) + (m << 3);  // wave-uniform LDS row base
      gll16(pa + (size_t)r0 * lda, smA + r0 * 64);
      gll16(pb + (size_t)r0 * ldb, smB + r0 * 64);
    }
    pa += BK; pb += BK;
    __syncthreads();  // drains vmcnt -> tiles resident

#pragma unroll
    for (int kk = 0; kk < BK; kk += 32) {
      bf16x8 af[4], bfr[4];
      const int kof = (kk + kquad) ^ swz;  // swizzled slot
#pragma unroll
      for (int i = 0; i < 4; i++)
        af[i] = *(const bf16x8*)(&smA[(rA + i * 16) * 64 + kof]);
#pragma unroll
      for (int j = 0; j < 4; j++)
        bfr[j] = *(const bf16x8*)(&smB[(rB + j * 16) * 64 + kof]);
#pragma unroll
      for (int i = 0; i < 4; i++)
#pragma unroll
        for (int j = 0; j < 4; j++)
          acc[i][j] = __builtin_amdgcn_mfma_f32_16x16x32_bf16(af[i], bfr[j],
                                                              acc[i][j], 0, 0, 0);
    }
  }

  // Epilogues. C/D layout: col = lane&15, row = (lane>>4)*4 + reg.
  float* Cf = (float*)Cout;
  unsigned short* Ch = (unsigned short*)Cout;
  const int colbase = bn * 128 + wn + (lane & 15);
  const int rowbase = bm * 128 + wm + ((lane >> 4) << 2);

  if (EPI == 0) {
    const bool isV = (bn >= 16);  // gc >= 2048: V third -> also emit V^T
#pragma unroll
    for (int i = 0; i < 4; i++)
#pragma unroll
      for (int j = 0; j < 4; j++) {
        const int gc = colbase + j * 16;
        const float cs = (gc < 1024) ? 0.03125f : 1.0f;
        const float bs = bias[gc];
        ushort4 h4;
        unsigned short* hp = (unsigned short*)&h4;
#pragma unroll
        for (int r = 0; r < 4; r++) {
          const int gr = rowbase + i * 16 + r;
          const unsigned short h = f2bf(acc[i][j][r] * cs + bs);
          Ch[(size_t)gr * ldc + gc] = h;
          hp[r] = h;
        }
        if (isV) {  // 4 consecutive rows of V^T column-run: one 8B store
          const int gr0 = rowbase + i * 16;
          *(ushort4*)(VT + (size_t)(gc - 2048) * N_TOK + gr0) = h4;
        }
      }
  } else if (EPI == 2) {
    // U = exp(score), causal; block row-sum -> atomicAdd into Lsum.
    __syncthreads();                 // all LDS reads done; repurpose smA
    float* Lp = (float*)smA;         // 128 floats
    if (t < 128) Lp[t] = 0.f;
    __syncthreads();
#pragma unroll
    for (int i = 0; i < 4; i++)
#pragma unroll
      for (int r = 0; r < 4; r++) {
        const int gr = rowbase + i * 16 + r;
        float sj = 0.f;
#pragma unroll
        for (int j = 0; j < 4; j++) {
          const int gc = colbase + j * 16;
          unsigned short h = 0;
          if (gc <= gr) h = f2bf(__expf(acc[i][j][r]));
          Ch[(size_t)gr * ldc + gc] = h;
          sj += bf2f(h);  // sum the rounded value so L matches stored U
        }
        sj += __shfl_xor(sj, 1);
        sj += __shfl_xor(sj, 2);
        sj += __shfl_xor(sj, 4);
        sj += __shfl_xor(sj, 8);
        if ((lane & 15) == 0)
          atomicAdd(&Lp[wm + ((lane >> 4) << 2) + i * 16 + r], sj);
      }
    __syncthreads();
    if (t < 128) atomicAdd(&Lsum[bm * 128 + t], Lp[t]);
  } else {
#pragma unroll
    for (int i = 0; i < 4; i++)
#pragma unroll
      for (int r = 0; r < 4; r++) {
        const int gr = rowbase + i * 16 + r;
        const float linv = 1.0f / Lsum[gr];
#pragma unroll
        for (int j = 0; j < 4; j++) {
          const int gc = colbase + j * 16;
          const float v = acc[i][j][r] * linv;
          if (single)
            Cf[(size_t)gr * ldc + gc] = v;
          else
            atomicAdd(&Cf[(size_t)gr * ldc + gc], v);
        }
      }
  }
}

// ---------------------------------------------------------------------------
// kernel_launch — 4 launches.  ws layout (ushort elems):
//   [0,4M)    xb [4096x1024]; after concat GEMM, reused as V^T [1024x4096]
//             (V^T written by EPI0's epilogue)
//   [4M,7M)   W_all^T = Wq^T | Wk^T | Wv^T  (3072 x 1024)
//   [7M,19M)  Call [4096x3072] = Q | K | V  (Q pre-scaled by 1/32)
//   [19M,35M) Sb [4096x4096]  (U = exp scores)
//   [35M,..)  ball [3072] f32, Lsum [4096] f32
// ---------------------------------------------------------------------------
extern "C" void kernel_launch(void* const* d_in, const int* in_sizes, int n_in,
                              void* d_out, int out_size, void* d_ws,
                              size_t ws_size, hipStream_t stream) {
  (void)in_sizes; (void)n_in; (void)out_size; (void)ws_size;
  const float* x  = (const float*)d_in[0];
  const float* Wq = (const float*)d_in[1];
  const float* bq = (const float*)d_in[2];
  const float* Wk = (const float*)d_in[3];
  const float* bk = (const float*)d_in[4];
  const float* Wv = (const float*)d_in[5];
  const float* bv = (const float*)d_in[6];
  float* out = (float*)d_out;

  const size_t M1 = (size_t)1024 * 1024;
  unsigned short* xb   = (unsigned short*)d_ws;   // 4M elems; later V^T
  unsigned short* Wt   = xb + 4 * M1;             // 3M elems
  unsigned short* Call = Wt + 3 * M1;             // 12M elems
  unsigned short* Sb   = Call + 12 * M1;          // 16M elems
  float* ball          = (float*)(Sb + 16 * M1);  // 3072 f32
  float* Lsum          = ball + 3072;             // 4096 f32

  // 1) all prep in one launch
  prep<<<PB_TOTAL, 256, 0, stream>>>(x, Wq, Wk, Wv, bq, bk, bv, xb, Wt, out,
                                     ball, Lsum);
  // 2) Call = x @ [Wq|Wk|Wv] + ball; V-third also scattered into xb as V^T.
  gemm_tn<0><<<dim3(24, 32), 256, 0, stream>>>(xb, Wt, Call, ball, nullptr,
                                               xb, DIM, DIM, DIM, 3 * DIM);
  // 3) U = exp(Q K^T) causal + row sums Lsum. 528 triangular blocks.
  gemm_tn<2><<<528, 256, 0, stream>>>(Call, Call + 1024, Sb, nullptr, Lsum,
                                      nullptr, DIM, 3 * DIM, 3 * DIM, N_TOK);
  // 4) O = (U V) / L, split-K chunk 512 (z<=8), 1152 blocks = 4.5/CU.
  gemm_tn<3><<<1152, 256, 0, stream>>>(Sb, xb, out, nullptr, Lsum, nullptr,
                                       N_TOK, N_TOK, N_TOK, DIM);
}

// Round 7
// 184.395 us; speedup vs baseline: 1.2075x; 1.2075x over previous
//
#include <hip/hip_runtime.h>

#define N_TOK 4096
#define DIM   1024

typedef __bf16 bf16x8 __attribute__((ext_vector_type(8)));
typedef float  f32x4  __attribute__((ext_vector_type(4)));

__device__ __forceinline__ unsigned short f2bf(float f) {
  union { float f; unsigned u; } v; v.f = f;
  unsigned u = v.u;
  return (unsigned short)((u + 0x7fffu + ((u >> 16) & 1u)) >> 16);
}
__device__ __forceinline__ float bf2f(unsigned short h) {
  union { unsigned u; float f; } v; v.u = ((unsigned)h) << 16;
  return v.f;
}

// async global->LDS, 16 B/lane: lane's data lands at (uniform lds base) + lane*16
__device__ __forceinline__ void gll16(const unsigned short* g,
                                      unsigned short* l) {
  __builtin_amdgcn_global_load_lds(
      (const __attribute__((address_space(1))) unsigned int*)g,
      (__attribute__((address_space(3))) unsigned int*)l, 16, 0, 0);
}

// ---------------------------------------------------------------------------
// prep kernel.
//   CVT writes x-bf16 into the Sb region (xs) — NOT xb. xb is now the
//   exclusive home of V^T (EPI0 epilogue), eliminating the round-5 latent
//   race (EPI0 wrote V^T into xb while other blocks read xb as A). Sb is
//   dead until EPI2 overwrites it, and EPI0 finishes before EPI2 starts.
//   ZERO job deleted: EPI3's z=0 chunks direct-store every out element.
// ---------------------------------------------------------------------------
#define PB_CVT 0
#define PB_TQ 2048
#define PB_LSUM 5120
#define PB_BIAS 5124
#define PB_TOTAL 5127

__global__ void prep(const float* __restrict__ x, const float* __restrict__ Wq,
                     const float* __restrict__ Wk, const float* __restrict__ Wv,
                     const float* __restrict__ bq, const float* __restrict__ bk,
                     const float* __restrict__ bv,
                     unsigned short* __restrict__ xs,
                     unsigned short* __restrict__ Wt,
                     float* __restrict__ ball, float* __restrict__ Lsum) {
  const int b = blockIdx.x;
  const int t = threadIdx.x;
  if (b < PB_TQ) {  // CVT: x f32 -> bf16 into xs (Sb scratch)
    const int i = ((b - PB_CVT) * 256 + t) * 8;
    float4 v0 = *(const float4*)(x + i);
    float4 v1 = *(const float4*)(x + i + 4);
    ushort4 r0, r1;
    r0.x = f2bf(v0.x); r0.y = f2bf(v0.y); r0.z = f2bf(v0.z); r0.w = f2bf(v0.w);
    r1.x = f2bf(v1.x); r1.y = f2bf(v1.y); r1.z = f2bf(v1.z); r1.w = f2bf(v1.w);
    *(ushort4*)(xs + i) = r0;
    *(ushort4*)(xs + i + 4) = r1;
  } else if (b < PB_LSUM) {  // transpose one 32x32 tile of one W
    const int which = (b - PB_TQ) >> 10;          // 0,1,2
    const int lb = (b - PB_TQ) & 1023;
    const float* W = (which == 0) ? Wq : (which == 1) ? Wk : Wv;
    unsigned short* D = Wt + (size_t)which * 1024 * 1024;
    __shared__ float tile[32][33];
    const int bx = (lb & 31) * 32, by = (lb >> 5) * 32;
    const int tx = t & 31, ty = t >> 5;  // ty in 0..7
    for (int r = ty; r < 32; r += 8)
      tile[r][tx] = W[(size_t)(by + r) * DIM + bx + tx];
    __syncthreads();
    for (int r = ty; r < 32; r += 8)
      D[(size_t)(bx + r) * DIM + by + tx] = f2bf(tile[tx][r]);
  } else if (b < PB_BIAS) {  // Lsum zero
    const int i = ((b - PB_LSUM) * 256 + t) * 4;
    *(float4*)(Lsum + i) = make_float4(0.f, 0.f, 0.f, 0.f);
  } else {  // bias, 4/thread
    const int i = ((b - PB_BIAS) * 256 + t) * 4;
#pragma unroll
    for (int c = 0; c < 4; c++) {
      const int k = i + c;
      if (k < 3072)
        ball[k] = (k < 1024) ? bq[k] * 0.03125f
                             : ((k < 2048) ? bk[k - 1024] : bv[k - 2048]);
    }
  }
}

// ---------------------------------------------------------------------------
// A·B^T MFMA GEMM — round-5 proven core (128x128 tile, 4 waves, BK=64,
// single-buffer 32 KB LDS drain loop, T2 swizzle with 0 conflicts,
// XCD-chunked swizzles on EPI0/EPI2).  This round's delta:
//  * EPI3 is ATOMIC-FREE (rounds 0/5/6 prove EPI3 was bound by a ~200-230
//    G/s f32-atomic ceiling, ~39 of 51.5 us): z=0 chunk direct-stores
//    acc*linv to out (sole writer per element); z>=1 chunks store acc*linv
//    to f32 partial bands in the dead Wt+Call region; reduce_out sums.
// EPI 0: QKV projection + fused V^T emission (A now reads xs=Sb-scratch).
// EPI 2: U = exp(score) causal + row sums -> Lsum (LDS + tiny atomics).
// EPI 3: O-chunks = (U V)*linv, 640-block compact z<=4 decode (proven).
// ---------------------------------------------------------------------------
#define BK 64

template <int EPI>
__global__ void gemm_tn(const unsigned short* __restrict__ A,
                        const unsigned short* __restrict__ B,
                        void* __restrict__ Cout,
                        const float* __restrict__ bias,
                        float* __restrict__ Lsum,
                        unsigned short* __restrict__ VT,
                        float* __restrict__ Part,
                        int K, int lda, int ldb, int ldc) {
  int bm, bn, kbeg, kend;
  int zz = 0, pidx = 0;
  if (EPI == 3) {
    // compact decode: i -> (bn, q); q -> (bm, z) by chunk-count bands
    const int i = blockIdx.x;       // 0..639
    bn = i & 7;                     // XCD-aligned V^T panel
    const int q = i >> 3;           // 0..79
    if (q < 8)       { bm = q;                    zz = 0; }
    else if (q < 24) { bm = 8 + ((q - 8) >> 1);   zz = (q - 8) & 1; }
    else if (q < 48) { bm = 16 + (q - 24) / 3;    zz = (q - 24) % 3; }
    else             { bm = 24 + ((q - 48) >> 2); zz = (q - 48) & 3; }
    const int Keff = (bm + 1) * 128;
    kbeg = zz * 1024;
    kend = min(kbeg + 1024, Keff);
    // partial band index for z>=1 (48 bands total)
    pidx = (bm < 16) ? (bm - 8)
         : (bm < 24) ? 8 + (bm - 16) * 2 + (zz - 1)
                     : 24 + (bm - 24) * 3 + (zz - 1);
  } else if (EPI == 2) {
    // XCD-chunked swizzle (528 = 8*66), then triangular decode
    const int id = blockIdx.x;
    const int wg = (id & 7) * 66 + (id >> 3);
    float s = sqrtf(8.f * (float)wg + 1.f);
    bm = (int)((s - 1.f) * 0.5f);
    while ((bm + 1) * (bm + 2) / 2 <= wg) ++bm;
    while (bm * (bm + 1) / 2 > wg) --bm;
    bn = wg - bm * (bm + 1) / 2;     // 0..bm
    kbeg = 0; kend = K;
  } else {
    // XCD-chunked swizzle (768 = 8*96)
    const int id = blockIdx.y * gridDim.x + blockIdx.x;
    const int wg = (id & 7) * 96 + (id >> 3);
    bm = wg / 24; bn = wg % 24;
    kbeg = 0; kend = K;
  }

  __shared__ __align__(16) unsigned short smA[128 * 64];
  __shared__ __align__(16) unsigned short smB[128 * 64];

  const int t = threadIdx.x;
  const int lane = t & 63, w = t >> 6;
  const int wm = (w & 1) * 64, wn = (w >> 1) * 64;

  f32x4 acc[4][4] = {};

  const unsigned short* Ab = A + (size_t)bm * 128 * lda;
  const unsigned short* Bb = B + (size_t)bn * 128 * ldb;

  const int rA = wm + (lane & 15);
  const int rB = wn + (lane & 15);
  const int kquad = (lane >> 4) << 3;
  const int swz = (lane & 7) << 3;   // read-side XOR (shorts)

  // staging source: row lr = lane>>3, chunk pre-XOR'd by lr so the linear
  // gll16 write matches the swizzled read (read rows have row&7 == lane&7).
  const int lr = lane >> 3;
  const int g8 = ((lane & 7) ^ lr) << 3;
  const unsigned short* pa = Ab + (size_t)lr * lda + g8 + kbeg;
  const unsigned short* pb = Bb + (size_t)lr * ldb + g8 + kbeg;

  for (int k0 = kbeg; k0 < kend; k0 += BK) {
    __syncthreads();
#pragma unroll
    for (int m = 0; m < 4; m++) {
      const int r0 = (w << 5) + (m << 3);  // wave-uniform LDS row base
      gll16(pa + (size_t)r0 * lda, smA + r0 * 64);
      gll16(pb + (size_t)r0 * ldb, smB + r0 * 64);
    }
    pa += BK; pb += BK;
    __syncthreads();  // drains vmcnt -> tiles resident

#pragma unroll
    for (int kk = 0; kk < BK; kk += 32) {
      bf16x8 af[4], bfr[4];
      const int kof = (kk + kquad) ^ swz;  // swizzled slot
#pragma unroll
      for (int i = 0; i < 4; i++)
        af[i] = *(const bf16x8*)(&smA[(rA + i * 16) * 64 + kof]);
#pragma unroll
      for (int j = 0; j < 4; j++)
        bfr[j] = *(const bf16x8*)(&smB[(rB + j * 16) * 64 + kof]);
#pragma unroll
      for (int i = 0; i < 4; i++)
#pragma unroll
        for (int j = 0; j < 4; j++)
          acc[i][j] = __builtin_amdgcn_mfma_f32_16x16x32_bf16(af[i], bfr[j],
                                                              acc[i][j], 0, 0, 0);
    }
  }

  // Epilogues. C/D layout: col = lane&15, row = (lane>>4)*4 + reg.
  float* Cf = (float*)Cout;
  unsigned short* Ch = (unsigned short*)Cout;
  const int colbase = bn * 128 + wn + (lane & 15);
  const int rowbase = bm * 128 + wm + ((lane >> 4) << 2);

  if (EPI == 0) {
    const bool isV = (bn >= 16);  // gc >= 2048: V third -> also emit V^T
#pragma unroll
    for (int i = 0; i < 4; i++)
#pragma unroll
      for (int j = 0; j < 4; j++) {
        const int gc = colbase + j * 16;
        const float cs = (gc < 1024) ? 0.03125f : 1.0f;
        const float bs = bias[gc];
        ushort4 h4;
        unsigned short* hp = (unsigned short*)&h4;
#pragma unroll
        for (int r = 0; r < 4; r++) {
          const int gr = rowbase + i * 16 + r;
          const unsigned short h = f2bf(acc[i][j][r] * cs + bs);
          Ch[(size_t)gr * ldc + gc] = h;
          hp[r] = h;
        }
        if (isV) {  // 4 consecutive rows of V^T column-run: one 8B store
          const int gr0 = rowbase + i * 16;
          *(ushort4*)(VT + (size_t)(gc - 2048) * N_TOK + gr0) = h4;
        }
      }
  } else if (EPI == 2) {
    // U = exp(score), causal; block row-sum -> atomicAdd into Lsum.
    __syncthreads();                 // all LDS reads done; repurpose smA
    float* Lp = (float*)smA;         // 128 floats
    if (t < 128) Lp[t] = 0.f;
    __syncthreads();
#pragma unroll
    for (int i = 0; i < 4; i++)
#pragma unroll
      for (int r = 0; r < 4; r++) {
        const int gr = rowbase + i * 16 + r;
        float sj = 0.f;
#pragma unroll
        for (int j = 0; j < 4; j++) {
          const int gc = colbase + j * 16;
          unsigned short h = 0;
          if (gc <= gr) h = f2bf(__expf(acc[i][j][r]));
          Ch[(size_t)gr * ldc + gc] = h;
          sj += bf2f(h);  // sum the rounded value so L matches stored U
        }
        sj += __shfl_xor(sj, 1);
        sj += __shfl_xor(sj, 2);
        sj += __shfl_xor(sj, 4);
        sj += __shfl_xor(sj, 8);
        if ((lane & 15) == 0)
          atomicAdd(&Lp[wm + ((lane >> 4) << 2) + i * 16 + r], sj);
      }
    __syncthreads();
    if (t < 128) atomicAdd(&Lsum[bm * 128 + t], Lp[t]);
  } else {
    // EPI 3: atomic-free. z=0 -> direct store into out (sole writer);
    // z>=1 -> f32 partial band (128x1024) at Part[pidx].
    float* dst = (zz == 0) ? (Cf + (size_t)bm * 128 * 1024)
                           : (Part + (size_t)pidx * 131072);
    const int colloc = bn * 128 + wn + (lane & 15);   // 0..1023
    const int rowloc = wm + ((lane >> 4) << 2);       // 0..127
#pragma unroll
    for (int i = 0; i < 4; i++)
#pragma unroll
      for (int r = 0; r < 4; r++) {
        const int rr = rowloc + i * 16 + r;
        const float linv = 1.0f / Lsum[bm * 128 + rr];
#pragma unroll
        for (int j = 0; j < 4; j++)
          dst[(size_t)rr * 1024 + colloc + j * 16] = acc[i][j][r] * linv;
      }
  }
}

// ---------------------------------------------------------------------------
// reduce_out: out rows [bm*128, +128) += sum of that bm's extra partial
// bands.  grid (24, 32): x = bm-8, y = 4-row slice. Pure float4 traffic.
// ---------------------------------------------------------------------------
__global__ void reduce_out(const float* __restrict__ Part,
                           float* __restrict__ out) {
  const int bm = 8 + blockIdx.x;
  const int sub = blockIdx.y;                          // 4-row slice
  const int extra = (bm < 16) ? 1 : (bm < 24) ? 2 : 3;
  const int pbase = (bm < 16) ? (bm - 8)
                  : (bm < 24) ? 8 + (bm - 16) * 2
                              : 24 + (bm - 24) * 3;
  const int t = threadIdx.x;
  float4* po = (float4*)(out + (size_t)(bm * 128 + sub * 4) * 1024);
  const float4* pp = (const float4*)(Part + (size_t)pbase * 131072 +
                                     (size_t)sub * 4096);
#pragma unroll
  for (int k = 0; k < 4; k++) {
    const int idx = t + k * 256;     // float4 index within 4096 floats
    float4 v = po[idx];
    for (int e = 0; e < extra; e++) {
      const float4 q = pp[(size_t)e * 32768 + idx];
      v.x += q.x; v.y += q.y; v.z += q.z; v.w += q.w;
    }
    po[idx] = v;
  }
}

// ---------------------------------------------------------------------------
// kernel_launch — 5 launches.  ws layout (ushort elems):
//   [0,4M)    V^T [1024x4096] bf16 (written by EPI0 epilogue, read by EPI3)
//   [4M,7M)   W_all^T (3072x1024) — dead after EPI0; reused by partials
//   [7M,19M)  Call [4096x3072] = Q | K | V — dead after EPI2
//             partials (f32, 48 x 128x1024 = 24 MB) live in [4M,16M)
//   [19M,35M) Sb [4096x4096] bf16: first 4M ushorts = x-bf16 scratch for
//             EPI0's A (written by prep, dead once EPI2 overwrites with U)
//   [35M,..)  ball [3072] f32, Lsum [4096] f32
// ---------------------------------------------------------------------------
extern "C" void kernel_launch(void* const* d_in, const int* in_sizes, int n_in,
                              void* d_out, int out_size, void* d_ws,
                              size_t ws_size, hipStream_t stream) {
  (void)in_sizes; (void)n_in; (void)out_size; (void)ws_size;
  const float* x  = (const float*)d_in[0];
  const float* Wq = (const float*)d_in[1];
  const float* bq = (const float*)d_in[2];
  const float* Wk = (const float*)d_in[3];
  const float* bk = (const float*)d_in[4];
  const float* Wv = (const float*)d_in[5];
  const float* bv = (const float*)d_in[6];
  float* out = (float*)d_out;

  const size_t M1 = (size_t)1024 * 1024;
  unsigned short* xb   = (unsigned short*)d_ws;   // V^T home
  unsigned short* Wt   = xb + 4 * M1;             // 3M elems (dead after EPI0)
  unsigned short* Call = Wt + 3 * M1;             // 12M elems
  unsigned short* Sb   = Call + 12 * M1;          // 16M elems
  float* ball          = (float*)(Sb + 16 * M1);  // 3072 f32
  float* Lsum          = ball + 3072;             // 4096 f32
  unsigned short* xs   = Sb;                      // x-bf16 scratch (8 MB)
  float* Part          = (float*)Wt;              // 24 MB partials [4M,16M)

  // 1) all prep in one launch (x->bf16 into xs, W^T, Lsum=0, bias)
  prep<<<PB_TOTAL, 256, 0, stream>>>(x, Wq, Wk, Wv, bq, bk, bv, xs, Wt,
                                     ball, Lsum);
  // 2) Call = x @ [Wq|Wk|Wv] + ball; V-third also scattered into xb as V^T.
  gemm_tn<0><<<dim3(24, 32), 256, 0, stream>>>(xs, Wt, Call, ball, nullptr,
                                               xb, nullptr, DIM, DIM, DIM,
                                               3 * DIM);
  // 3) U = exp(Q K^T) causal + row sums Lsum. 528 triangular blocks.
  gemm_tn<2><<<528, 256, 0, stream>>>(Call, Call + 1024, Sb, nullptr, Lsum,
                                      nullptr, nullptr, DIM, 3 * DIM, 3 * DIM,
                                      N_TOK);
  // 4) O-chunks = (U V)*linv, compact 640-block split-K, atomic-free.
  gemm_tn<3><<<640, 256, 0, stream>>>(Sb, xb, out, nullptr, Lsum, nullptr,
                                      Part, N_TOK, N_TOK, N_TOK, DIM);
  // 5) out += partials for bm>=8.
  reduce_out<<<dim3(24, 32), 256, 0, stream>>>(Part, out);
}